// Round 4
// baseline (16020.554 us; speedup 1.0000x reference)
//
#include <hip/hip_runtime.h>
#include <hip/hip_cooperative_groups.h>

#define BDIM 64
#define TDIM 1024
#define IDIM 512
#define HDIM 512
#define G4   2048

typedef unsigned short u16;
typedef unsigned int u32;
typedef unsigned long long u64;
typedef __attribute__((ext_vector_type(8))) short short8;
typedef __attribute__((ext_vector_type(4))) float f32x4;

__device__ __forceinline__ u16 f2bf(float f) {
    union { float f; unsigned u; } v; v.f = f;
    unsigned u = v.u;
    return (u16)((u + 0x7fffu + ((u >> 16) & 1u)) >> 16);
}
__device__ __forceinline__ float bf2f(u16 h) {
    union { unsigned u; float f; } v; v.u = ((unsigned)h) << 16;
    return v.f;
}
__device__ __forceinline__ float sigmoidf_(float x) {
    return 1.0f / (1.0f + expf(-x));
}

// ---------------------------------------------------------------------------
// prep: cast W_hh -> bf16, bias = b_ih + b_hh, w_full[t], zero h dbuf + flags
// ---------------------------------------------------------------------------
__global__ void prep_kernel(const float* __restrict__ Whh,
                            const float* __restrict__ bih,
                            const float* __restrict__ bhh,
                            const float* __restrict__ log_phi,
                            const float* __restrict__ gammas,
                            u16* __restrict__ whh_bf,
                            float* __restrict__ bias,
                            float* __restrict__ wfull,
                            u16* __restrict__ hbuf,
                            u32* __restrict__ flags) {
    int idx = blockIdx.x * 256 + threadIdx.x;
    if (idx < G4 * HDIM) whh_bf[idx] = f2bf(Whh[idx]);
    if (idx < G4) bias[idx] = bih[idx] + bhh[idx];
    if (idx < 2 * BDIM * HDIM) hbuf[idx] = 0;
    if (idx < 128) flags[idx] = 0;
    if (idx < TDIM) {
        float acc = 0.0f;
        #pragma unroll
        for (int m = 0; m < 15; ++m) {
            float lp = log_phi[m];
            float sp = (lp > 15.0f) ? lp : log1pf(expf(lp));
            acc += sp * cosf((float)idx * gammas[m]);
        }
        wfull[idx] = 0.4f * acc / 15.0f;
    }
}

// ---------------------------------------------------------------------------
// xproj GEMM: [65536 x 2048] = x[65536 x 512] * W_ih[2048 x 512]^T + bias
// Output layout: xproj[t][b][n] bf16.
// ---------------------------------------------------------------------------
__global__ __launch_bounds__(256) void xproj_gemm(
        const float* __restrict__ X, const float* __restrict__ Wih,
        const float* __restrict__ bias, u16* __restrict__ xproj) {
    const int tid  = threadIdx.x;
    const int m0   = blockIdx.x * 128;
    const int n0   = blockIdx.y * 128;
    const int lane = tid & 63, w = tid >> 6;
    const int l16  = lane & 15, lhi = lane >> 4;
    const int wr   = w >> 1, wc = w & 1;

    __shared__ u16 As[128 * 64];
    __shared__ u16 Bs[128 * 64];

    f32x4 acc[4][4];
    #pragma unroll
    for (int i = 0; i < 4; ++i)
        #pragma unroll
        for (int j = 0; j < 4; ++j) acc[i][j] = (f32x4){0.f, 0.f, 0.f, 0.f};

    for (int kt = 0; kt < 8; ++kt) {
        const int k0 = kt * 64;
        __syncthreads();
        #pragma unroll
        for (int p = 0; p < 4; ++p) {
            int g = p * 256 + tid;
            int row = g >> 3, oct = g & 7;
            const float* src = X + (size_t)(m0 + row) * IDIM + k0 + oct * 8;
            float4 v0 = *(const float4*)src;
            float4 v1 = *(const float4*)(src + 4);
            short8 u;
            u[0] = (short)f2bf(v0.x); u[1] = (short)f2bf(v0.y);
            u[2] = (short)f2bf(v0.z); u[3] = (short)f2bf(v0.w);
            u[4] = (short)f2bf(v1.x); u[5] = (short)f2bf(v1.y);
            u[6] = (short)f2bf(v1.z); u[7] = (short)f2bf(v1.w);
            int so = (oct ^ (row & 7)) * 8;
            *(short8*)&As[row * 64 + so] = u;
        }
        #pragma unroll
        for (int p = 0; p < 4; ++p) {
            int g = p * 256 + tid;
            int row = g >> 3, oct = g & 7;
            const float* src = Wih + (size_t)(n0 + row) * IDIM + k0 + oct * 8;
            float4 v0 = *(const float4*)src;
            float4 v1 = *(const float4*)(src + 4);
            short8 u;
            u[0] = (short)f2bf(v0.x); u[1] = (short)f2bf(v0.y);
            u[2] = (short)f2bf(v0.z); u[3] = (short)f2bf(v0.w);
            u[4] = (short)f2bf(v1.x); u[5] = (short)f2bf(v1.y);
            u[6] = (short)f2bf(v1.z); u[7] = (short)f2bf(v1.w);
            int so = (oct ^ (row & 7)) * 8;
            *(short8*)&Bs[row * 64 + so] = u;
        }
        __syncthreads();
        #pragma unroll
        for (int ks = 0; ks < 2; ++ks) {
            short8 a[4], b[4];
            #pragma unroll
            for (int ai = 0; ai < 4; ++ai) {
                int row = 64 * wr + 16 * ai + l16;
                int oct = (4 * ks + lhi) ^ (row & 7);
                a[ai] = *(const short8*)&As[row * 64 + oct * 8];
            }
            #pragma unroll
            for (int bi = 0; bi < 4; ++bi) {
                int row = 64 * wc + 16 * bi + l16;
                int oct = (4 * ks + lhi) ^ (row & 7);
                b[bi] = *(const short8*)&Bs[row * 64 + oct * 8];
            }
            #pragma unroll
            for (int ai = 0; ai < 4; ++ai)
                #pragma unroll
                for (int bi = 0; bi < 4; ++bi)
                    acc[ai][bi] = __builtin_amdgcn_mfma_f32_16x16x32_bf16(
                        a[ai], b[bi], acc[ai][bi], 0, 0, 0);
        }
    }
    float bv[4];
    #pragma unroll
    for (int bi = 0; bi < 4; ++bi) bv[bi] = bias[n0 + 64 * wc + 16 * bi + l16];
    #pragma unroll
    for (int ai = 0; ai < 4; ++ai) {
        int grow_base = m0 + 64 * wr + 16 * ai + 4 * lhi;
        #pragma unroll
        for (int bi = 0; bi < 4; ++bi) {
            int gcol = n0 + 64 * wc + 16 * bi + l16;
            #pragma unroll
            for (int r = 0; r < 4; ++r) {
                int grow = grow_base + r;
                int b = grow >> 10;
                int t = grow & 1023;
                xproj[((size_t)t * BDIM + b) * G4 + gcol] =
                    f2bf(acc[ai][bi][r] + bv[bi]);
            }
        }
    }
}

// ---------------------------------------------------------------------------
// scan v4: 16 blocks x 256 threads; each block owns 32 h-columns and
// time-multiplexes the 4 independent batch groups per t-step, so each
// group's L3 sync latency is overlapped with the other groups' compute.
// hbuf layout: [buf][g(4)][src_blk(16)][ln(64)][j(8)] bf16.
// flags[g*32 + blk] = t+1 after block blk stored its h slice of group g.
// ---------------------------------------------------------------------------
__global__ __launch_bounds__(256, 1) void scan_kernel(
        const u16* __restrict__ whh_bf, const float* __restrict__ wfull,
        const u16* __restrict__ xproj, u16* __restrict__ hbuf,
        u32* __restrict__ flags, float* __restrict__ out) {
    const int tid = threadIdx.x;
    const int blk = blockIdx.x;      // 0..15 column block
    const int c0  = blk * 32;
    const int lane = tid & 63, w = tid >> 6;
    const int l16 = lane & 15, lhi = lane >> 4;

    __shared__ float gates[16 * 128];   // reused by the 4 group phases
    __shared__ float wt_s[TDIM];

    for (int i = tid; i < TDIM; i += 256) wt_s[i] = wfull[i];

    // W_hh B-fragments resident in regs (shared by all 4 groups):
    // wave w = gate w, cols c0+l16 and c0+16+l16.
    short8 Bf0[16], Bf1[16];
    #pragma unroll
    for (int ks = 0; ks < 16; ++ks) {
        int row0 = w * HDIM + c0 + l16;
        int row1 = w * HDIM + c0 + 16 + l16;
        Bf0[ks] = *(const short8*)&whh_bf[(size_t)row0 * HDIM + ks * 32 + lhi * 8];
        Bf1[ks] = *(const short8*)&whh_bf[(size_t)row1 * HDIM + ks * 32 + lhi * 8];
    }

    // elementwise ownership: thread -> (batch-in-group eb, cols j0, j0+1)
    const int eb = tid >> 4;
    const int j0 = 2 * (tid & 15);
    const int ln_e = eb + 16 * (j0 >> 3);
    const size_t eoff = (size_t)ln_e * 8 + (j0 & 7);   // within a 512-elem slice

    float creg[4][2];
    float ho[4][2];
    u32   xq[4][4];
    #pragma unroll
    for (int g = 0; g < 4; ++g) { creg[g][0] = 0.f; creg[g][1] = 0.f; }

    // prologue: prefetch xproj[t=0] for all groups
    #pragma unroll
    for (int g = 0; g < 4; ++g) {
        const u16* xb = xproj + (size_t)(g * 16 + eb) * G4 + c0 + j0;
        xq[g][0] = *(const u32*)(xb + 0 * HDIM);
        xq[g][1] = *(const u32*)(xb + 1 * HDIM);
        xq[g][2] = *(const u32*)(xb + 2 * HDIM);
        xq[g][3] = *(const u32*)(xb + 3 * HDIM);
    }
    __syncthreads();

    for (int t = 0; t < TDIM; ++t) {
        const int cur = t & 1;
        const size_t bufc = (size_t)cur * (BDIM * HDIM);
        const size_t bufn = (size_t)(cur ^ 1) * (BDIM * HDIM);

        #pragma unroll
        for (int g = 0; g < 4; ++g) {
            // ---- wait for h[t] of group g (all 16 producers) ----
            if (t > 0) {
                const u32 target = (u32)t;
                u32 v;
                do {
                    v = (lane < 16)
                        ? __hip_atomic_load(&flags[g * 32 + lane],
                                            __ATOMIC_RELAXED, __HIP_MEMORY_SCOPE_AGENT)
                        : 0xffffffffu;
                } while (!__all(v >= target));
            }

            // ---- A-fragments: L3 -> reg ----
            const u16* hsrc = hbuf + bufc + (size_t)g * (16 * HDIM);
            short8 a[16];
            #pragma unroll
            for (int ks = 0; ks < 16; ++ks) {
                const u64* p = (const u64*)(hsrc + ks * 512 + lane * 8);
                u64 lo = __hip_atomic_load(p, __ATOMIC_RELAXED, __HIP_MEMORY_SCOPE_AGENT);
                u64 hi = __hip_atomic_load(p + 1, __ATOMIC_RELAXED, __HIP_MEMORY_SCOPE_AGENT);
                union { u64 q[2]; short8 s; } uu; uu.q[0] = lo; uu.q[1] = hi;
                a[ks] = uu.s;
            }
            u32 hpu = __hip_atomic_load(
                (const u32*)(hbuf + bufc + (size_t)(g * 16 + blk) * 512 + eoff),
                __ATOMIC_RELAXED, __HIP_MEMORY_SCOPE_AGENT);

            // ---- gates GEMM tile ----
            f32x4 acc0 = {0.f, 0.f, 0.f, 0.f}, acc1 = {0.f, 0.f, 0.f, 0.f};
            #pragma unroll
            for (int ks = 0; ks < 16; ++ks) {
                acc0 = __builtin_amdgcn_mfma_f32_16x16x32_bf16(a[ks], Bf0[ks], acc0, 0, 0, 0);
                acc1 = __builtin_amdgcn_mfma_f32_16x16x32_bf16(a[ks], Bf1[ks], acc1, 0, 0, 0);
            }
            #pragma unroll
            for (int r = 0; r < 4; ++r) {
                gates[(4 * lhi + r) * 128 + w * 32 + l16]      = acc0[r];
                gates[(4 * lhi + r) * 128 + w * 32 + 16 + l16] = acc1[r];
            }
            __syncthreads();

            // ---- elementwise LSTM + zeta ----
            const float wt = wt_s[t];
            float x0 = bf2f((u16)(xq[g][0] & 0xffff)), x1 = bf2f((u16)(xq[g][0] >> 16));
            float f0 = bf2f((u16)(xq[g][1] & 0xffff)), f1 = bf2f((u16)(xq[g][1] >> 16));
            float g0 = bf2f((u16)(xq[g][2] & 0xffff)), g1 = bf2f((u16)(xq[g][2] >> 16));
            float o0 = bf2f((u16)(xq[g][3] & 0xffff)), o1 = bf2f((u16)(xq[g][3] >> 16));

            float gi0 = gates[eb * 128 + 0 * 32 + j0]     + x0;
            float gi1 = gates[eb * 128 + 0 * 32 + j0 + 1] + x1;
            float gf0 = gates[eb * 128 + 1 * 32 + j0]     + f0;
            float gf1 = gates[eb * 128 + 1 * 32 + j0 + 1] + f1;
            float gg0 = gates[eb * 128 + 2 * 32 + j0]     + g0;
            float gg1 = gates[eb * 128 + 2 * 32 + j0 + 1] + g1;
            float go0 = gates[eb * 128 + 3 * 32 + j0]     + o0;
            float go1 = gates[eb * 128 + 3 * 32 + j0 + 1] + o1;

            float hp0 = bf2f((u16)(hpu & 0xffff)), hp1 = bf2f((u16)(hpu >> 16));

            float cn0 = sigmoidf_(gf0) * creg[g][0] + sigmoidf_(gi0) * tanhf(gg0);
            float cn1 = sigmoidf_(gf1) * creg[g][1] + sigmoidf_(gi1) * tanhf(gg1);
            float h0 = sigmoidf_(go0) * tanhf(cn0) + wt * hp0;
            float h1 = sigmoidf_(go1) * tanhf(cn1) + wt * hp1;
            creg[g][0] = cn0; creg[g][1] = cn1;
            ho[g][0] = h0; ho[g][1] = h1;

            // ---- publish h[t+1] slice, ack, flag ----
            u32 hw = (u32)f2bf(h0) | ((u32)f2bf(h1) << 16);
            __hip_atomic_store(
                (u32*)(hbuf + bufn + (size_t)(g * 16 + blk) * 512 + eoff), hw,
                __ATOMIC_RELAXED, __HIP_MEMORY_SCOPE_AGENT);
            asm volatile("s_waitcnt vmcnt(0)" ::: "memory");
            __syncthreads();
            if (tid == 0 && t + 1 < TDIM)
                __hip_atomic_store(&flags[g * 32 + blk], (u32)(t + 1),
                                   __ATOMIC_RELAXED, __HIP_MEMORY_SCOPE_AGENT);
        }

        // ---- superstep tail: out-stores + next prefetch (off critical path) --
        if (t == TDIM - 1) {
            #pragma unroll
            for (int g = 0; g < 4; ++g) {
                int b = g * 16 + eb;
                *(float2*)(out + ((size_t)b * TDIM + t) * HDIM + c0 + j0) =
                    make_float2(ho[g][0], ho[g][1]);
                size_t base = (size_t)BDIM * TDIM * HDIM;
                *(float2*)(out + base + (size_t)b * HDIM + c0 + j0) =
                    make_float2(ho[g][0], ho[g][1]);
                *(float2*)(out + base + (size_t)BDIM * HDIM +
                           (size_t)b * HDIM + c0 + j0) =
                    make_float2(creg[g][0], creg[g][1]);
            }
        } else {
            #pragma unroll
            for (int g = 0; g < 4; ++g) {
                int b = g * 16 + eb;
                *(float2*)(out + ((size_t)b * TDIM + t) * HDIM + c0 + j0) =
                    make_float2(ho[g][0], ho[g][1]);
                const u16* xb = xproj + (size_t)(t + 1) * BDIM * G4 +
                                (size_t)b * G4 + c0 + j0;
                xq[g][0] = *(const u32*)(xb + 0 * HDIM);
                xq[g][1] = *(const u32*)(xb + 1 * HDIM);
                xq[g][2] = *(const u32*)(xb + 2 * HDIM);
                xq[g][3] = *(const u32*)(xb + 3 * HDIM);
            }
        }
    }
}

// ---------------------------------------------------------------------------
extern "C" void kernel_launch(void* const* d_in, const int* in_sizes, int n_in,
                              void* d_out, int out_size, void* d_ws, size_t ws_size,
                              hipStream_t stream) {
    const float* x       = (const float*)d_in[0];
    const float* Wih     = (const float*)d_in[1];
    const float* Whh     = (const float*)d_in[2];
    const float* bih     = (const float*)d_in[3];
    const float* bhh     = (const float*)d_in[4];
    const float* log_phi = (const float*)d_in[5];
    const float* gammas  = (const float*)d_in[6];
    float* out = (float*)d_out;

    char* ws = (char*)d_ws;
    u16*   whh_bf = (u16*)(ws);                               // 2 MB
    float* bias   = (float*)(ws + (2u << 20));                // 8 KB
    float* wfull  = (float*)(ws + (2u << 20) + 8192);         // 4 KB
    u32*   flags  = (u32*)(ws + (2u << 20) + 12288);          // 512 B (4 x 128B)
    u16*   hbuf   = (u16*)(ws + (2u << 20) + 16384);          // 128 KB
    u16*   xproj  = (u16*)(ws + (4u << 20));                  // 256 MB

    prep_kernel<<<dim3(4096), dim3(256), 0, stream>>>(
        Whh, bih, bhh, log_phi, gammas, whh_bf, bias, wfull, hbuf, flags);

    xproj_gemm<<<dim3(512, 16), dim3(256), 0, stream>>>(x, Wih, bias, xproj);

    void* args[] = { (void*)&whh_bf, (void*)&wfull, (void*)&xproj,
                     (void*)&hbuf, (void*)&flags, (void*)&out };
    hipLaunchCooperativeKernel((void*)scan_kernel, dim3(16), dim3(256),
                               args, 0, stream);
}

// Round 6
// 3620.224 us; speedup vs baseline: 4.4253x; 4.4253x over previous
//
#include <hip/hip_runtime.h>

#define BDIM 64
#define TDIM 1024
#define IDIM 512
#define HDIM 512
#define G4   2048
#define DSLAB 8
// slab = full h snapshot in MFMA-frag layout: [group(4)][ks(16)][lane(64)][j(8)]
#define SLAB_ELEMS (BDIM * HDIM)          // 32768 u16 = 64 KB
#define GROUP_ELEMS (16 * HDIM)           // 8192 u16 = 16 KB

typedef unsigned short u16;
typedef unsigned int u32;
typedef unsigned long long u64;
typedef __attribute__((ext_vector_type(8))) short short8;
typedef __attribute__((ext_vector_type(4))) float f32x4;

__device__ __forceinline__ u16 f2bf(float f) {
    union { float f; unsigned u; } v; v.f = f;
    unsigned u = v.u;
    return (u16)((u + 0x7fffu + ((u >> 16) & 1u)) >> 16);
}
__device__ __forceinline__ float bf2f(u16 h) {
    union { unsigned u; float f; } v; v.u = ((unsigned)h) << 16;
    return v.f;
}
__device__ __forceinline__ float sigmoidf_(float x) {
    return 1.0f / (1.0f + expf(-x));
}

// ---------------------------------------------------------------------------
// prep: cast W_hh -> bf16, bias = b_ih + b_hh, w_full[t];
// hbuf ring: slab 0 = zeros (h0), slabs 1..7 = 0xFFFFFFFF poison.
// ---------------------------------------------------------------------------
__global__ void prep_kernel(const float* __restrict__ Whh,
                            const float* __restrict__ bih,
                            const float* __restrict__ bhh,
                            const float* __restrict__ log_phi,
                            const float* __restrict__ gammas,
                            u16* __restrict__ whh_bf,
                            float* __restrict__ bias,
                            float* __restrict__ wfull,
                            u32* __restrict__ hbuf32) {
    int idx = blockIdx.x * 256 + threadIdx.x;
    if (idx < G4 * HDIM) whh_bf[idx] = f2bf(Whh[idx]);
    if (idx < G4) bias[idx] = bih[idx] + bhh[idx];
    if (idx < DSLAB * (SLAB_ELEMS / 2))
        hbuf32[idx] = (idx < (SLAB_ELEMS / 2)) ? 0u : 0xffffffffu;
    if (idx < TDIM) {
        float acc = 0.0f;
        #pragma unroll
        for (int m = 0; m < 15; ++m) {
            float lp = log_phi[m];
            float sp = (lp > 15.0f) ? lp : log1pf(expf(lp));
            acc += sp * cosf((float)idx * gammas[m]);
        }
        wfull[idx] = 0.4f * acc / 15.0f;
    }
}

// ---------------------------------------------------------------------------
// xproj GEMM: [65536 x 2048] = x[65536 x 512] * W_ih[2048 x 512]^T + bias
// Output layout: xproj[t][b][n] bf16.
// ---------------------------------------------------------------------------
__global__ __launch_bounds__(256) void xproj_gemm(
        const float* __restrict__ X, const float* __restrict__ Wih,
        const float* __restrict__ bias, u16* __restrict__ xproj) {
    const int tid  = threadIdx.x;
    const int m0   = blockIdx.x * 128;
    const int n0   = blockIdx.y * 128;
    const int lane = tid & 63, w = tid >> 6;
    const int l16  = lane & 15, lhi = lane >> 4;
    const int wr   = w >> 1, wc = w & 1;

    __shared__ u16 As[128 * 64];
    __shared__ u16 Bs[128 * 64];

    f32x4 acc[4][4];
    #pragma unroll
    for (int i = 0; i < 4; ++i)
        #pragma unroll
        for (int j = 0; j < 4; ++j) acc[i][j] = (f32x4){0.f, 0.f, 0.f, 0.f};

    for (int kt = 0; kt < 8; ++kt) {
        const int k0 = kt * 64;
        __syncthreads();
        #pragma unroll
        for (int p = 0; p < 4; ++p) {
            int g = p * 256 + tid;
            int row = g >> 3, oct = g & 7;
            const float* src = X + (size_t)(m0 + row) * IDIM + k0 + oct * 8;
            float4 v0 = *(const float4*)src;
            float4 v1 = *(const float4*)(src + 4);
            short8 u;
            u[0] = (short)f2bf(v0.x); u[1] = (short)f2bf(v0.y);
            u[2] = (short)f2bf(v0.z); u[3] = (short)f2bf(v0.w);
            u[4] = (short)f2bf(v1.x); u[5] = (short)f2bf(v1.y);
            u[6] = (short)f2bf(v1.z); u[7] = (short)f2bf(v1.w);
            int so = (oct ^ (row & 7)) * 8;
            *(short8*)&As[row * 64 + so] = u;
        }
        #pragma unroll
        for (int p = 0; p < 4; ++p) {
            int g = p * 256 + tid;
            int row = g >> 3, oct = g & 7;
            const float* src = Wih + (size_t)(n0 + row) * IDIM + k0 + oct * 8;
            float4 v0 = *(const float4*)src;
            float4 v1 = *(const float4*)(src + 4);
            short8 u;
            u[0] = (short)f2bf(v0.x); u[1] = (short)f2bf(v0.y);
            u[2] = (short)f2bf(v0.z); u[3] = (short)f2bf(v0.w);
            u[4] = (short)f2bf(v1.x); u[5] = (short)f2bf(v1.y);
            u[6] = (short)f2bf(v1.z); u[7] = (short)f2bf(v1.w);
            int so = (oct ^ (row & 7)) * 8;
            *(short8*)&Bs[row * 64 + so] = u;
        }
        __syncthreads();
        #pragma unroll
        for (int ks = 0; ks < 2; ++ks) {
            short8 a[4], b[4];
            #pragma unroll
            for (int ai = 0; ai < 4; ++ai) {
                int row = 64 * wr + 16 * ai + l16;
                int oct = (4 * ks + lhi) ^ (row & 7);
                a[ai] = *(const short8*)&As[row * 64 + oct * 8];
            }
            #pragma unroll
            for (int bi = 0; bi < 4; ++bi) {
                int row = 64 * wc + 16 * bi + l16;
                int oct = (4 * ks + lhi) ^ (row & 7);
                b[bi] = *(const short8*)&Bs[row * 64 + oct * 8];
            }
            #pragma unroll
            for (int ai = 0; ai < 4; ++ai)
                #pragma unroll
                for (int bi = 0; bi < 4; ++bi)
                    acc[ai][bi] = __builtin_amdgcn_mfma_f32_16x16x32_bf16(
                        a[ai], b[bi], acc[ai][bi], 0, 0, 0);
        }
    }
    float bv[4];
    #pragma unroll
    for (int bi = 0; bi < 4; ++bi) bv[bi] = bias[n0 + 64 * wc + 16 * bi + l16];
    #pragma unroll
    for (int ai = 0; ai < 4; ++ai) {
        int grow_base = m0 + 64 * wr + 16 * ai + 4 * lhi;
        #pragma unroll
        for (int bi = 0; bi < 4; ++bi) {
            int gcol = n0 + 64 * wc + 16 * bi + l16;
            #pragma unroll
            for (int r = 0; r < 4; ++r) {
                int grow = grow_base + r;
                int b = grow >> 10;
                int t = grow & 1023;
                xproj[((size_t)t * BDIM + b) * G4 + gcol] =
                    f2bf(acc[ai][bi][r] + bv[bi]);
            }
        }
    }
}

// ---------------------------------------------------------------------------
// scan v6: 64 blocks x 256 threads (4 groups x 16 col-blocks), PLAIN launch
// (no grid.sync anywhere; 64 blocks on an idle 256-CU device are co-resident).
// No flags: h exchanged through an 8-deep slab ring; consumers retry-load the
// data itself until no bf16 0xFFFF poison. Producers re-poison their word in
// slab (t-1) each step (provably after all its readers). One syncthreads/step.
// ---------------------------------------------------------------------------
__global__ __launch_bounds__(256, 1) void scan_kernel(
        const u16* __restrict__ whh_bf, const float* __restrict__ wfull,
        const u16* __restrict__ xproj, u16* __restrict__ hbuf,
        float* __restrict__ out) {
    const int tid = threadIdx.x;
    const int blk = blockIdx.x;      // 0..63
    const int bg  = blk >> 4;        // 0..3   batch group (16 batches)
    const int cgp = blk & 15;        // 0..15  col group (32 h-cols)
    const int b0  = bg * 16;
    const int c0  = cgp * 32;
    const int lane = tid & 63, w = tid >> 6;
    const int l16 = lane & 15, lhi = lane >> 4;

    __shared__ float gbuf[2][16 * 128];   // double-buffered gates
    __shared__ float wt_s[TDIM];

    for (int i = tid; i < TDIM; i += 256) wt_s[i] = wfull[i];

    // W_hh B-fragments resident in regs: wave w = gate w, cols c0+l16, c0+16+l16
    short8 Bf0[16], Bf1[16];
    #pragma unroll
    for (int ks = 0; ks < 16; ++ks) {
        int row0 = w * HDIM + c0 + l16;
        int row1 = w * HDIM + c0 + 16 + l16;
        Bf0[ks] = *(const short8*)&whh_bf[(size_t)row0 * HDIM + ks * 32 + lhi * 8];
        Bf1[ks] = *(const short8*)&whh_bf[(size_t)row1 * HDIM + ks * 32 + lhi * 8];
    }

    // elementwise ownership: thread -> (b = tid>>4, cols j0 = 2*(tid&15), j0+1)
    const int eb = tid >> 4;
    const int j0 = 2 * (tid & 15);
    const int gcol = c0 + j0;
    const int ln_e = eb + 16 * (j0 >> 3);
    const size_t eidx = ((size_t)cgp * 64 + ln_e) * 8 + (j0 & 7); // u16 idx, even
    float creg0 = 0.f, creg1 = 0.f;      // cell state
    float hp0 = 0.f, hp1 = 0.f;          // previous h (zeta), in-register

    // prologue: prefetch xproj[t=0]
    u32 xq0, xq1, xq2, xq3;
    {
        const u16* xb = xproj + (size_t)(b0 + eb) * G4 + gcol;
        xq0 = *(const u32*)(xb + 0 * HDIM);
        xq1 = *(const u32*)(xb + 1 * HDIM);
        xq2 = *(const u32*)(xb + 2 * HDIM);
        xq3 = *(const u32*)(xb + 3 * HDIM);
    }
    __syncthreads();

    for (int t = 0; t < TDIM; ++t) {
        const u16* hsrc = hbuf + (size_t)(t & 7) * SLAB_ELEMS
                               + (size_t)bg * GROUP_ELEMS;

        // ---- A-fragments: retry-load from L3 until no poison ----
        union F { u64 q[2]; short8 s; } A[16];
        for (;;) {
            u32 bad = 0;
            #pragma unroll
            for (int ks = 0; ks < 16; ++ks) {
                const u64* p = (const u64*)(hsrc + ks * 512 + lane * 8);
                u64 lo = __hip_atomic_load(p, __ATOMIC_RELAXED, __HIP_MEMORY_SCOPE_AGENT);
                u64 hi = __hip_atomic_load(p + 1, __ATOMIC_RELAXED, __HIP_MEMORY_SCOPE_AGENT);
                A[ks].q[0] = lo; A[ks].q[1] = hi;
                bad |= ((u32)lo == 0xffffffffu) | ((u32)(lo >> 32) == 0xffffffffu) |
                       ((u32)hi == 0xffffffffu) | ((u32)(hi >> 32) == 0xffffffffu);
            }
            if (!__any((int)bad)) break;
        }

        // ---- gates GEMM tile ----
        f32x4 acc0 = {0.f, 0.f, 0.f, 0.f}, acc1 = {0.f, 0.f, 0.f, 0.f};
        #pragma unroll
        for (int ks = 0; ks < 16; ++ks) {
            acc0 = __builtin_amdgcn_mfma_f32_16x16x32_bf16(A[ks].s, Bf0[ks], acc0, 0, 0, 0);
            acc1 = __builtin_amdgcn_mfma_f32_16x16x32_bf16(A[ks].s, Bf1[ks], acc1, 0, 0, 0);
        }
        float* gb = gbuf[t & 1];
        #pragma unroll
        for (int r = 0; r < 4; ++r) {
            gb[(4 * lhi + r) * 128 + w * 32 + l16]      = acc0[r];
            gb[(4 * lhi + r) * 128 + w * 32 + 16 + l16] = acc1[r];
        }
        __syncthreads();

        // ---- elementwise LSTM + zeta (h_prev from registers) ----
        const float wt = wt_s[t];
        float x0 = bf2f((u16)(xq0 & 0xffff)), x1 = bf2f((u16)(xq0 >> 16));
        float f0 = bf2f((u16)(xq1 & 0xffff)), f1 = bf2f((u16)(xq1 >> 16));
        float g0 = bf2f((u16)(xq2 & 0xffff)), g1 = bf2f((u16)(xq2 >> 16));
        float o0 = bf2f((u16)(xq3 & 0xffff)), o1 = bf2f((u16)(xq3 >> 16));

        float gi0 = gb[eb * 128 + 0 * 32 + j0]     + x0;
        float gi1 = gb[eb * 128 + 0 * 32 + j0 + 1] + x1;
        float gf0 = gb[eb * 128 + 1 * 32 + j0]     + f0;
        float gf1 = gb[eb * 128 + 1 * 32 + j0 + 1] + f1;
        float gg0 = gb[eb * 128 + 2 * 32 + j0]     + g0;
        float gg1 = gb[eb * 128 + 2 * 32 + j0 + 1] + g1;
        float go0 = gb[eb * 128 + 3 * 32 + j0]     + o0;
        float go1 = gb[eb * 128 + 3 * 32 + j0 + 1] + o1;

        float cn0 = sigmoidf_(gf0) * creg0 + sigmoidf_(gi0) * tanhf(gg0);
        float cn1 = sigmoidf_(gf1) * creg1 + sigmoidf_(gi1) * tanhf(gg1);
        float ho0 = sigmoidf_(go0) * tanhf(cn0) + wt * hp0;
        float ho1 = sigmoidf_(go1) * tanhf(cn1) + wt * hp1;
        creg0 = cn0; creg1 = cn1;
        hp0 = ho0; hp1 = ho1;

        // ---- publish h[t+1] (single store, no ack wait) ----
        u32 hw = (u32)f2bf(ho0) | ((u32)f2bf(ho1) << 16);
        __hip_atomic_store(
            (u32*)(hbuf + (size_t)((t + 1) & 7) * SLAB_ELEMS +
                   (size_t)bg * GROUP_ELEMS + eidx), hw,
            __ATOMIC_RELAXED, __HIP_MEMORY_SCOPE_AGENT);
        // re-poison slab (t-1): all its readers are provably done
        if (t > 0)
            __hip_atomic_store(
                (u32*)(hbuf + (size_t)((t - 1) & 7) * SLAB_ELEMS +
                       (size_t)bg * GROUP_ELEMS + eidx), 0xffffffffu,
                __ATOMIC_RELAXED, __HIP_MEMORY_SCOPE_AGENT);

        // ---- off-critical-path: out store + next xproj prefetch ----
        *(float2*)(out + ((size_t)(b0 + eb) * TDIM + t) * HDIM + gcol) =
            make_float2(ho0, ho1);
        if (t == TDIM - 1) {
            size_t base = (size_t)BDIM * TDIM * HDIM;
            *(float2*)(out + base + (size_t)(b0 + eb) * HDIM + gcol) =
                make_float2(ho0, ho1);
            *(float2*)(out + base + (size_t)BDIM * HDIM +
                       (size_t)(b0 + eb) * HDIM + gcol) =
                make_float2(cn0, cn1);
        } else {
            const u16* xb = xproj + (size_t)(t + 1) * BDIM * G4 +
                            (size_t)(b0 + eb) * G4 + gcol;
            xq0 = *(const u32*)(xb + 0 * HDIM);
            xq1 = *(const u32*)(xb + 1 * HDIM);
            xq2 = *(const u32*)(xb + 2 * HDIM);
            xq3 = *(const u32*)(xb + 3 * HDIM);
        }
    }
}

// ---------------------------------------------------------------------------
extern "C" void kernel_launch(void* const* d_in, const int* in_sizes, int n_in,
                              void* d_out, int out_size, void* d_ws, size_t ws_size,
                              hipStream_t stream) {
    const float* x       = (const float*)d_in[0];
    const float* Wih     = (const float*)d_in[1];
    const float* Whh     = (const float*)d_in[2];
    const float* bih     = (const float*)d_in[3];
    const float* bhh     = (const float*)d_in[4];
    const float* log_phi = (const float*)d_in[5];
    const float* gammas  = (const float*)d_in[6];
    float* out = (float*)d_out;

    char* ws = (char*)d_ws;
    u16*   whh_bf = (u16*)(ws);                               // 2 MB
    float* bias   = (float*)(ws + (2u << 20));                // 8 KB
    float* wfull  = (float*)(ws + (2u << 20) + 8192);         // 4 KB
    u16*   hbuf   = (u16*)(ws + (3u << 20));                  // 512 KB ring
    u16*   xproj  = (u16*)(ws + (4u << 20));                  // 256 MB

    prep_kernel<<<dim3(4096), dim3(256), 0, stream>>>(
        Whh, bih, bhh, log_phi, gammas, whh_bf, bias, wfull, (u32*)hbuf);

    xproj_gemm<<<dim3(512, 16), dim3(256), 0, stream>>>(x, Wih, bias, xproj);

    scan_kernel<<<dim3(64), dim3(256), 0, stream>>>(
        whh_bf, wfull, xproj, hbuf, out);
}

// Round 7
// 2865.025 us; speedup vs baseline: 5.5918x; 1.2636x over previous
//
#include <hip/hip_runtime.h>

#define BDIM 64
#define TDIM 1024
#define IDIM 512
#define HDIM 512
#define G4   2048
#define DSLAB 8
// slab = full h snapshot in MFMA-frag layout: [group(4)][ks(16)][lane(64)][j(8)]
#define SLAB_ELEMS (BDIM * HDIM)          // 32768 u16 = 64 KB
#define GROUP_ELEMS (16 * HDIM)           // 8192 u16 = 16 KB

typedef unsigned short u16;
typedef unsigned int u32;
typedef unsigned long long u64;
typedef __attribute__((ext_vector_type(8))) short short8;
typedef __attribute__((ext_vector_type(4))) float f32x4;

__device__ __forceinline__ u16 f2bf(float f) {
    union { float f; unsigned u; } v; v.f = f;
    unsigned u = v.u;
    return (u16)((u + 0x7fffu + ((u >> 16) & 1u)) >> 16);
}
__device__ __forceinline__ float bf2f(u16 h) {
    union { unsigned u; float f; } v; v.u = ((unsigned)h) << 16;
    return v.f;
}
__device__ __forceinline__ float sigmoidf_(float x) {
    return 1.0f / (1.0f + expf(-x));
}

// ---------------------------------------------------------------------------
// prep: cast W_hh -> bf16, bias = b_ih + b_hh, w_full[t];
// hbuf ring: slab 0 = zeros (h0), slabs 1..7 = 0xFFFFFFFF poison.
// ---------------------------------------------------------------------------
__global__ void prep_kernel(const float* __restrict__ Whh,
                            const float* __restrict__ bih,
                            const float* __restrict__ bhh,
                            const float* __restrict__ log_phi,
                            const float* __restrict__ gammas,
                            u16* __restrict__ whh_bf,
                            float* __restrict__ bias,
                            float* __restrict__ wfull,
                            u32* __restrict__ hbuf32) {
    int idx = blockIdx.x * 256 + threadIdx.x;
    if (idx < G4 * HDIM) whh_bf[idx] = f2bf(Whh[idx]);
    if (idx < G4) bias[idx] = bih[idx] + bhh[idx];
    if (idx < DSLAB * (SLAB_ELEMS / 2))
        hbuf32[idx] = (idx < (SLAB_ELEMS / 2)) ? 0u : 0xffffffffu;
    if (idx < TDIM) {
        float acc = 0.0f;
        #pragma unroll
        for (int m = 0; m < 15; ++m) {
            float lp = log_phi[m];
            float sp = (lp > 15.0f) ? lp : log1pf(expf(lp));
            acc += sp * cosf((float)idx * gammas[m]);
        }
        wfull[idx] = 0.4f * acc / 15.0f;
    }
}

// ---------------------------------------------------------------------------
// xproj GEMM: [65536 x 2048] = x[65536 x 512] * W_ih[2048 x 512]^T + bias
// Output layout: xproj[t][b][n] bf16.
// ---------------------------------------------------------------------------
__global__ __launch_bounds__(256) void xproj_gemm(
        const float* __restrict__ X, const float* __restrict__ Wih,
        const float* __restrict__ bias, u16* __restrict__ xproj) {
    const int tid  = threadIdx.x;
    const int m0   = blockIdx.x * 128;
    const int n0   = blockIdx.y * 128;
    const int lane = tid & 63, w = tid >> 6;
    const int l16  = lane & 15, lhi = lane >> 4;
    const int wr   = w >> 1, wc = w & 1;

    __shared__ u16 As[128 * 64];
    __shared__ u16 Bs[128 * 64];

    f32x4 acc[4][4];
    #pragma unroll
    for (int i = 0; i < 4; ++i)
        #pragma unroll
        for (int j = 0; j < 4; ++j) acc[i][j] = (f32x4){0.f, 0.f, 0.f, 0.f};

    for (int kt = 0; kt < 8; ++kt) {
        const int k0 = kt * 64;
        __syncthreads();
        #pragma unroll
        for (int p = 0; p < 4; ++p) {
            int g = p * 256 + tid;
            int row = g >> 3, oct = g & 7;
            const float* src = X + (size_t)(m0 + row) * IDIM + k0 + oct * 8;
            float4 v0 = *(const float4*)src;
            float4 v1 = *(const float4*)(src + 4);
            short8 u;
            u[0] = (short)f2bf(v0.x); u[1] = (short)f2bf(v0.y);
            u[2] = (short)f2bf(v0.z); u[3] = (short)f2bf(v0.w);
            u[4] = (short)f2bf(v1.x); u[5] = (short)f2bf(v1.y);
            u[6] = (short)f2bf(v1.z); u[7] = (short)f2bf(v1.w);
            int so = (oct ^ (row & 7)) * 8;
            *(short8*)&As[row * 64 + so] = u;
        }
        #pragma unroll
        for (int p = 0; p < 4; ++p) {
            int g = p * 256 + tid;
            int row = g >> 3, oct = g & 7;
            const float* src = Wih + (size_t)(n0 + row) * IDIM + k0 + oct * 8;
            float4 v0 = *(const float4*)src;
            float4 v1 = *(const float4*)(src + 4);
            short8 u;
            u[0] = (short)f2bf(v0.x); u[1] = (short)f2bf(v0.y);
            u[2] = (short)f2bf(v0.z); u[3] = (short)f2bf(v0.w);
            u[4] = (short)f2bf(v1.x); u[5] = (short)f2bf(v1.y);
            u[6] = (short)f2bf(v1.z); u[7] = (short)f2bf(v1.w);
            int so = (oct ^ (row & 7)) * 8;
            *(short8*)&Bs[row * 64 + so] = u;
        }
        __syncthreads();
        #pragma unroll
        for (int ks = 0; ks < 2; ++ks) {
            short8 a[4], b[4];
            #pragma unroll
            for (int ai = 0; ai < 4; ++ai) {
                int row = 64 * wr + 16 * ai + l16;
                int oct = (4 * ks + lhi) ^ (row & 7);
                a[ai] = *(const short8*)&As[row * 64 + oct * 8];
            }
            #pragma unroll
            for (int bi = 0; bi < 4; ++bi) {
                int row = 64 * wc + 16 * bi + l16;
                int oct = (4 * ks + lhi) ^ (row & 7);
                b[bi] = *(const short8*)&Bs[row * 64 + oct * 8];
            }
            #pragma unroll
            for (int ai = 0; ai < 4; ++ai)
                #pragma unroll
                for (int bi = 0; bi < 4; ++bi)
                    acc[ai][bi] = __builtin_amdgcn_mfma_f32_16x16x32_bf16(
                        a[ai], b[bi], acc[ai][bi], 0, 0, 0);
        }
    }
    float bv[4];
    #pragma unroll
    for (int bi = 0; bi < 4; ++bi) bv[bi] = bias[n0 + 64 * wc + 16 * bi + l16];
    #pragma unroll
    for (int ai = 0; ai < 4; ++ai) {
        int grow_base = m0 + 64 * wr + 16 * ai + 4 * lhi;
        #pragma unroll
        for (int bi = 0; bi < 4; ++bi) {
            int gcol = n0 + 64 * wc + 16 * bi + l16;
            #pragma unroll
            for (int r = 0; r < 4; ++r) {
                int grow = grow_base + r;
                int b = grow >> 10;
                int t = grow & 1023;
                xproj[((size_t)t * BDIM + b) * G4 + gcol] =
                    f2bf(acc[ai][bi][r] + bv[bi]);
            }
        }
    }
}

// ---------------------------------------------------------------------------
// scan v7: 64 blocks x 256 threads (4 groups x 16 col-blocks), plain launch.
// Poison slab ring as v6, but WAVE-SPLIT POLLING: wave w polls only its 4 of
// 16 ks-fragments (4 KB), stages them to LDS; all waves then read all 16
// fragments from LDS. Device poll traffic /4 -> less MALL queueing.
// ---------------------------------------------------------------------------
__global__ __launch_bounds__(256, 1) void scan_kernel(
        const u16* __restrict__ whh_bf, const float* __restrict__ wfull,
        const u16* __restrict__ xproj, u16* __restrict__ hbuf,
        float* __restrict__ out) {
    const int tid = threadIdx.x;
    const int blk = blockIdx.x;      // 0..63
    const int bg  = blk >> 4;        // 0..3   batch group (16 batches)
    const int cgp = blk & 15;        // 0..15  col group (32 h-cols)
    const int b0  = bg * 16;
    const int c0  = cgp * 32;
    const int lane = tid & 63, w = tid >> 6;
    const int l16 = lane & 15, lhi = lane >> 4;

    __shared__ u16  hfrag[16 * 64 * 8];   // 16 KB: staged A fragments
    __shared__ float gates[16 * 128];     //  8 KB (single buffer)
    __shared__ float wt_s[TDIM];          //  4 KB

    for (int i = tid; i < TDIM; i += 256) wt_s[i] = wfull[i];

    // W_hh B-fragments resident in regs: wave w = gate w, cols c0+l16, c0+16+l16
    short8 Bf0[16], Bf1[16];
    #pragma unroll
    for (int ks = 0; ks < 16; ++ks) {
        int row0 = w * HDIM + c0 + l16;
        int row1 = w * HDIM + c0 + 16 + l16;
        Bf0[ks] = *(const short8*)&whh_bf[(size_t)row0 * HDIM + ks * 32 + lhi * 8];
        Bf1[ks] = *(const short8*)&whh_bf[(size_t)row1 * HDIM + ks * 32 + lhi * 8];
    }

    // elementwise ownership: thread -> (b = tid>>4, cols j0 = 2*(tid&15), j0+1)
    const int eb = tid >> 4;
    const int j0 = 2 * (tid & 15);
    const int gcol = c0 + j0;
    const int ln_e = eb + 16 * (j0 >> 3);
    const size_t eidx = ((size_t)cgp * 64 + ln_e) * 8 + (j0 & 7); // u16 idx, even
    float creg0 = 0.f, creg1 = 0.f;      // cell state
    float hp0 = 0.f, hp1 = 0.f;          // previous h (zeta), in-register

    // prologue: prefetch xproj[t=0]
    u32 xq0, xq1, xq2, xq3;
    {
        const u16* xb = xproj + (size_t)(b0 + eb) * G4 + gcol;
        xq0 = *(const u32*)(xb + 0 * HDIM);
        xq1 = *(const u32*)(xb + 1 * HDIM);
        xq2 = *(const u32*)(xb + 2 * HDIM);
        xq3 = *(const u32*)(xb + 3 * HDIM);
    }
    __syncthreads();

    for (int t = 0; t < TDIM; ++t) {
        const u16* hsrc = hbuf + (size_t)(t & 7) * SLAB_ELEMS
                               + (size_t)bg * GROUP_ELEMS;

        // ---- wave w polls ONLY its 4 ks fragments until poison-free ----
        union F { u64 q[2]; short8 s; } A4[4];
        for (;;) {
            u32 bad = 0;
            #pragma unroll
            for (int i = 0; i < 4; ++i) {
                const int ks = 4 * w + i;
                const u64* p = (const u64*)(hsrc + ks * 512 + lane * 8);
                u64 lo = __hip_atomic_load(p, __ATOMIC_RELAXED, __HIP_MEMORY_SCOPE_AGENT);
                u64 hi = __hip_atomic_load(p + 1, __ATOMIC_RELAXED, __HIP_MEMORY_SCOPE_AGENT);
                A4[i].q[0] = lo; A4[i].q[1] = hi;
                bad |= ((u32)lo == 0xffffffffu) | ((u32)(lo >> 32) == 0xffffffffu) |
                       ((u32)hi == 0xffffffffu) | ((u32)(hi >> 32) == 0xffffffffu);
            }
            if (!__any((int)bad)) break;
        }
        // stage own fragments to LDS
        #pragma unroll
        for (int i = 0; i < 4; ++i) {
            const int ks = 4 * w + i;
            *(short8*)&hfrag[(ks * 64 + lane) * 8] = A4[i].s;
        }
        __syncthreads();

        // ---- gates GEMM tile: A from LDS, B from regs ----
        f32x4 acc0 = {0.f, 0.f, 0.f, 0.f}, acc1 = {0.f, 0.f, 0.f, 0.f};
        #pragma unroll
        for (int ks = 0; ks < 16; ++ks) {
            short8 a = *(const short8*)&hfrag[(ks * 64 + lane) * 8];
            acc0 = __builtin_amdgcn_mfma_f32_16x16x32_bf16(a, Bf0[ks], acc0, 0, 0, 0);
            acc1 = __builtin_amdgcn_mfma_f32_16x16x32_bf16(a, Bf1[ks], acc1, 0, 0, 0);
        }
        #pragma unroll
        for (int r = 0; r < 4; ++r) {
            gates[(4 * lhi + r) * 128 + w * 32 + l16]      = acc0[r];
            gates[(4 * lhi + r) * 128 + w * 32 + 16 + l16] = acc1[r];
        }
        __syncthreads();

        // ---- elementwise LSTM + zeta (h_prev from registers) ----
        const float wt = wt_s[t];
        float x0 = bf2f((u16)(xq0 & 0xffff)), x1 = bf2f((u16)(xq0 >> 16));
        float f0 = bf2f((u16)(xq1 & 0xffff)), f1 = bf2f((u16)(xq1 >> 16));
        float g0 = bf2f((u16)(xq2 & 0xffff)), g1 = bf2f((u16)(xq2 >> 16));
        float o0 = bf2f((u16)(xq3 & 0xffff)), o1 = bf2f((u16)(xq3 >> 16));

        float gi0 = gates[eb * 128 + 0 * 32 + j0]     + x0;
        float gi1 = gates[eb * 128 + 0 * 32 + j0 + 1] + x1;
        float gf0 = gates[eb * 128 + 1 * 32 + j0]     + f0;
        float gf1 = gates[eb * 128 + 1 * 32 + j0 + 1] + f1;
        float gg0 = gates[eb * 128 + 2 * 32 + j0]     + g0;
        float gg1 = gates[eb * 128 + 2 * 32 + j0 + 1] + g1;
        float go0 = gates[eb * 128 + 3 * 32 + j0]     + o0;
        float go1 = gates[eb * 128 + 3 * 32 + j0 + 1] + o1;

        float cn0 = sigmoidf_(gf0) * creg0 + sigmoidf_(gi0) * tanhf(gg0);
        float cn1 = sigmoidf_(gf1) * creg1 + sigmoidf_(gi1) * tanhf(gg1);
        float ho0 = sigmoidf_(go0) * tanhf(cn0) + wt * hp0;
        float ho1 = sigmoidf_(go1) * tanhf(cn1) + wt * hp1;
        creg0 = cn0; creg1 = cn1;
        hp0 = ho0; hp1 = ho1;

        // ---- publish h[t+1] (single store, no ack wait) ----
        u32 hw = (u32)f2bf(ho0) | ((u32)f2bf(ho1) << 16);
        __hip_atomic_store(
            (u32*)(hbuf + (size_t)((t + 1) & 7) * SLAB_ELEMS +
                   (size_t)bg * GROUP_ELEMS + eidx), hw,
            __ATOMIC_RELAXED, __HIP_MEMORY_SCOPE_AGENT);
        // re-poison slab (t-1): all its readers are provably done
        if (t > 0)
            __hip_atomic_store(
                (u32*)(hbuf + (size_t)((t - 1) & 7) * SLAB_ELEMS +
                       (size_t)bg * GROUP_ELEMS + eidx), 0xffffffffu,
                __ATOMIC_RELAXED, __HIP_MEMORY_SCOPE_AGENT);

        // ---- off-critical-path: out store + next xproj prefetch ----
        *(float2*)(out + ((size_t)(b0 + eb) * TDIM + t) * HDIM + gcol) =
            make_float2(ho0, ho1);
        if (t == TDIM - 1) {
            size_t base = (size_t)BDIM * TDIM * HDIM;
            *(float2*)(out + base + (size_t)(b0 + eb) * HDIM + gcol) =
                make_float2(ho0, ho1);
            *(float2*)(out + base + (size_t)BDIM * HDIM +
                       (size_t)(b0 + eb) * HDIM + gcol) =
                make_float2(cn0, cn1);
        } else {
            const u16* xb = xproj + (size_t)(t + 1) * BDIM * G4 +
                            (size_t)(b0 + eb) * G4 + gcol;
            xq0 = *(const u32*)(xb + 0 * HDIM);
            xq1 = *(const u32*)(xb + 1 * HDIM);
            xq2 = *(const u32*)(xb + 2 * HDIM);
            xq3 = *(const u32*)(xb + 3 * HDIM);
        }
    }
}

// ---------------------------------------------------------------------------
extern "C" void kernel_launch(void* const* d_in, const int* in_sizes, int n_in,
                              void* d_out, int out_size, void* d_ws, size_t ws_size,
                              hipStream_t stream) {
    const float* x       = (const float*)d_in[0];
    const float* Wih     = (const float*)d_in[1];
    const float* Whh     = (const float*)d_in[2];
    const float* bih     = (const float*)d_in[3];
    const float* bhh     = (const float*)d_in[4];
    const float* log_phi = (const float*)d_in[5];
    const float* gammas  = (const float*)d_in[6];
    float* out = (float*)d_out;

    char* ws = (char*)d_ws;
    u16*   whh_bf = (u16*)(ws);                               // 2 MB
    float* bias   = (float*)(ws + (2u << 20));                // 8 KB
    float* wfull  = (float*)(ws + (2u << 20) + 8192);         // 4 KB
    u16*   hbuf   = (u16*)(ws + (3u << 20));                  // 512 KB ring
    u16*   xproj  = (u16*)(ws + (4u << 20));                  // 256 MB

    prep_kernel<<<dim3(4096), dim3(256), 0, stream>>>(
        Whh, bih, bhh, log_phi, gammas, whh_bf, bias, wfull, (u32*)hbuf);

    xproj_gemm<<<dim3(512, 16), dim3(256), 0, stream>>>(x, Wih, bias, xproj);

    scan_kernel<<<dim3(64), dim3(256), 0, stream>>>(
        whh_bf, wfull, xproj, hbuf, out);
}

// Round 9
// 2721.584 us; speedup vs baseline: 5.8865x; 1.0527x over previous
//
#include <hip/hip_runtime.h>

#define BDIM 64
#define TDIM 1024
#define IDIM 512
#define HDIM 512
#define G4   2048
#define DSLAB 8
// slab = full h snapshot in MFMA-frag layout: [group(4)][ks(16)][lane(64)][j(8)]
#define SLAB_ELEMS (BDIM * HDIM)          // 32768 u16 = 64 KB
#define GROUP_ELEMS (16 * HDIM)           // 8192 u16 = 16 KB

typedef unsigned short u16;
typedef unsigned int u32;
typedef unsigned long long u64;
typedef __attribute__((ext_vector_type(8))) short short8;
typedef __attribute__((ext_vector_type(4))) float f32x4;

__device__ __forceinline__ u16 f2bf(float f) {
    union { float f; unsigned u; } v; v.f = f;
    unsigned u = v.u;
    return (u16)((u + 0x7fffu + ((u >> 16) & 1u)) >> 16);
}
__device__ __forceinline__ float bf2f(u16 h) {
    union { unsigned u; float f; } v; v.u = ((unsigned)h) << 16;
    return v.f;
}
// fast saturation-safe sigmoid/tanh on v_exp_f32 + v_rcp_f32 (~1 ulp; bf16
// rounding dominates). sig(-inf)=0, sig(+inf)=1, tanh(+-inf)=+-1 — no NaN.
__device__ __forceinline__ float fsig(float x) {
    float e = __builtin_amdgcn_exp2f(x * -1.4426950408889634f);
    return __builtin_amdgcn_rcpf(1.0f + e);
}
__device__ __forceinline__ float ftanh(float x) {
    float e = __builtin_amdgcn_exp2f(x * -2.8853900817779268f);
    return 2.0f * __builtin_amdgcn_rcpf(1.0f + e) - 1.0f;
}

// ---------------------------------------------------------------------------
// prep: cast W_hh -> bf16, bias = b_ih + b_hh, w_full[t];
// hbuf ring: slab 0 = zeros (h0), slabs 1..7 = 0xFFFFFFFF poison.
// ---------------------------------------------------------------------------
__global__ void prep_kernel(const float* __restrict__ Whh,
                            const float* __restrict__ bih,
                            const float* __restrict__ bhh,
                            const float* __restrict__ log_phi,
                            const float* __restrict__ gammas,
                            u16* __restrict__ whh_bf,
                            float* __restrict__ bias,
                            float* __restrict__ wfull,
                            u32* __restrict__ hbuf32) {
    int idx = blockIdx.x * 256 + threadIdx.x;
    if (idx < G4 * HDIM) whh_bf[idx] = f2bf(Whh[idx]);
    if (idx < G4) bias[idx] = bih[idx] + bhh[idx];
    if (idx < DSLAB * (SLAB_ELEMS / 2))
        hbuf32[idx] = (idx < (SLAB_ELEMS / 2)) ? 0u : 0xffffffffu;
    if (idx < TDIM) {
        float acc = 0.0f;
        #pragma unroll
        for (int m = 0; m < 15; ++m) {
            float lp = log_phi[m];
            float sp = (lp > 15.0f) ? lp : log1pf(expf(lp));
            acc += sp * cosf((float)idx * gammas[m]);
        }
        wfull[idx] = 0.4f * acc / 15.0f;
    }
}

// ---------------------------------------------------------------------------
// xproj GEMM: [65536 x 2048] = x[65536 x 512] * W_ih[2048 x 512]^T + bias
// Output layout: xproj[t][b][n] bf16.
// ---------------------------------------------------------------------------
__global__ __launch_bounds__(256) void xproj_gemm(
        const float* __restrict__ X, const float* __restrict__ Wih,
        const float* __restrict__ bias, u16* __restrict__ xproj) {
    const int tid  = threadIdx.x;
    const int m0   = blockIdx.x * 128;
    const int n0   = blockIdx.y * 128;
    const int lane = tid & 63, w = tid >> 6;
    const int l16  = lane & 15, lhi = lane >> 4;
    const int wr   = w >> 1, wc = w & 1;

    __shared__ u16 As[128 * 64];
    __shared__ u16 Bs[128 * 64];

    f32x4 acc[4][4];
    #pragma unroll
    for (int i = 0; i < 4; ++i)
        #pragma unroll
        for (int j = 0; j < 4; ++j) acc[i][j] = (f32x4){0.f, 0.f, 0.f, 0.f};

    for (int kt = 0; kt < 8; ++kt) {
        const int k0 = kt * 64;
        __syncthreads();
        #pragma unroll
        for (int p = 0; p < 4; ++p) {
            int g = p * 256 + tid;
            int row = g >> 3, oct = g & 7;
            const float* src = X + (size_t)(m0 + row) * IDIM + k0 + oct * 8;
            float4 v0 = *(const float4*)src;
            float4 v1 = *(const float4*)(src + 4);
            short8 u;
            u[0] = (short)f2bf(v0.x); u[1] = (short)f2bf(v0.y);
            u[2] = (short)f2bf(v0.z); u[3] = (short)f2bf(v0.w);
            u[4] = (short)f2bf(v1.x); u[5] = (short)f2bf(v1.y);
            u[6] = (short)f2bf(v1.z); u[7] = (short)f2bf(v1.w);
            int so = (oct ^ (row & 7)) * 8;
            *(short8*)&As[row * 64 + so] = u;
        }
        #pragma unroll
        for (int p = 0; p < 4; ++p) {
            int g = p * 256 + tid;
            int row = g >> 3, oct = g & 7;
            const float* src = Wih + (size_t)(n0 + row) * IDIM + k0 + oct * 8;
            float4 v0 = *(const float4*)src;
            float4 v1 = *(const float4*)(src + 4);
            short8 u;
            u[0] = (short)f2bf(v0.x); u[1] = (short)f2bf(v0.y);
            u[2] = (short)f2bf(v0.z); u[3] = (short)f2bf(v0.w);
            u[4] = (short)f2bf(v1.x); u[5] = (short)f2bf(v1.y);
            u[6] = (short)f2bf(v1.z); u[7] = (short)f2bf(v1.w);
            int so = (oct ^ (row & 7)) * 8;
            *(short8*)&Bs[row * 64 + so] = u;
        }
        __syncthreads();
        #pragma unroll
        for (int ks = 0; ks < 2; ++ks) {
            short8 a[4], b[4];
            #pragma unroll
            for (int ai = 0; ai < 4; ++ai) {
                int row = 64 * wr + 16 * ai + l16;
                int oct = (4 * ks + lhi) ^ (row & 7);
                a[ai] = *(const short8*)&As[row * 64 + oct * 8];
            }
            #pragma unroll
            for (int bi = 0; bi < 4; ++bi) {
                int row = 64 * wc + 16 * bi + l16;
                int oct = (4 * ks + lhi) ^ (row & 7);
                b[bi] = *(const short8*)&Bs[row * 64 + oct * 8];
            }
            #pragma unroll
            for (int ai = 0; ai < 4; ++ai)
                #pragma unroll
                for (int bi = 0; bi < 4; ++bi)
                    acc[ai][bi] = __builtin_amdgcn_mfma_f32_16x16x32_bf16(
                        a[ai], b[bi], acc[ai][bi], 0, 0, 0);
        }
    }
    float bv[4];
    #pragma unroll
    for (int bi = 0; bi < 4; ++bi) bv[bi] = bias[n0 + 64 * wc + 16 * bi + l16];
    #pragma unroll
    for (int ai = 0; ai < 4; ++ai) {
        int grow_base = m0 + 64 * wr + 16 * ai + 4 * lhi;
        #pragma unroll
        for (int bi = 0; bi < 4; ++bi) {
            int gcol = n0 + 64 * wc + 16 * bi + l16;
            #pragma unroll
            for (int r = 0; r < 4; ++r) {
                int grow = grow_base + r;
                int b = grow >> 10;
                int t = grow & 1023;
                xproj[((size_t)t * BDIM + b) * G4 + gcol] =
                    f2bf(acc[ai][bi][r] + bv[bi]);
            }
        }
    }
}

// ---------------------------------------------------------------------------
// scan v9: 64 blocks x 256 threads (4 groups x 16 col-blocks), plain launch.
// Poison slab ring + wave-split polling (v7). Early-issue vmem (out[t-1]
// store, xproj[t+1] prefetch) right after poll-detect so it drains under
// compute. Re-poison of slab t-1 happens AFTER the staging __syncthreads():
// only then has the whole block verified slab t completeness (all 4 waves'
// polls passed), which is the proof that every reader of slab t-1 is done.
// (v8's pre-barrier re-poison was the deadlock.)
// ---------------------------------------------------------------------------
__global__ __launch_bounds__(256, 1) void scan_kernel(
        const u16* __restrict__ whh_bf, const float* __restrict__ wfull,
        const u16* __restrict__ xproj, u16* __restrict__ hbuf,
        float* __restrict__ out) {
    const int tid = threadIdx.x;
    const int blk = blockIdx.x;      // 0..63
    const int bg  = blk >> 4;        // 0..3   batch group (16 batches)
    const int cgp = blk & 15;        // 0..15  col group (32 h-cols)
    const int b0  = bg * 16;
    const int c0  = cgp * 32;
    const int lane = tid & 63, w = tid >> 6;
    const int l16 = lane & 15, lhi = lane >> 4;

    __shared__ u16  hfrag[16 * 64 * 8];   // 16 KB: staged A fragments
    __shared__ float gates[16 * 128];     //  8 KB (single buffer)
    __shared__ float wt_s[TDIM];          //  4 KB

    for (int i = tid; i < TDIM; i += 256) wt_s[i] = wfull[i];

    // W_hh B-fragments resident in regs: wave w = gate w, cols c0+l16, c0+16+l16
    short8 Bf0[16], Bf1[16];
    #pragma unroll
    for (int ks = 0; ks < 16; ++ks) {
        int row0 = w * HDIM + c0 + l16;
        int row1 = w * HDIM + c0 + 16 + l16;
        Bf0[ks] = *(const short8*)&whh_bf[(size_t)row0 * HDIM + ks * 32 + lhi * 8];
        Bf1[ks] = *(const short8*)&whh_bf[(size_t)row1 * HDIM + ks * 32 + lhi * 8];
    }

    // elementwise ownership: thread -> (b = tid>>4, cols j0 = 2*(tid&15), j0+1)
    const int eb = tid >> 4;
    const int j0 = 2 * (tid & 15);
    const int gcol = c0 + j0;
    const int ln_e = eb + 16 * (j0 >> 3);
    const size_t eidx = ((size_t)cgp * 64 + ln_e) * 8 + (j0 & 7); // u16 idx, even
    float creg0 = 0.f, creg1 = 0.f;      // cell state
    float hp0 = 0.f, hp1 = 0.f;          // previous h (zeta + deferred out store)

    // prologue: xq_cur = xproj[t=0]
    u32 xq0, xq1, xq2, xq3;
    {
        const u16* xb = xproj + (size_t)(b0 + eb) * G4 + gcol;
        xq0 = *(const u32*)(xb + 0 * HDIM);
        xq1 = *(const u32*)(xb + 1 * HDIM);
        xq2 = *(const u32*)(xb + 2 * HDIM);
        xq3 = *(const u32*)(xb + 3 * HDIM);
    }
    __syncthreads();

    for (int t = 0; t < TDIM; ++t) {
        const u16* hsrc = hbuf + (size_t)(t & 7) * SLAB_ELEMS
                               + (size_t)bg * GROUP_ELEMS;

        // ---- wave w polls ONLY its 4 ks fragments until poison-free ----
        union F { u64 q[2]; short8 s; } A4[4];
        for (;;) {
            u32 bad = 0;
            #pragma unroll
            for (int i = 0; i < 4; ++i) {
                const int ks = 4 * w + i;
                const u64* p = (const u64*)(hsrc + ks * 512 + lane * 8);
                u64 lo = __hip_atomic_load(p, __ATOMIC_RELAXED, __HIP_MEMORY_SCOPE_AGENT);
                u64 hi = __hip_atomic_load(p + 1, __ATOMIC_RELAXED, __HIP_MEMORY_SCOPE_AGENT);
                A4[i].q[0] = lo; A4[i].q[1] = hi;
                bad |= ((u32)lo == 0xffffffffu) | ((u32)(lo >> 32) == 0xffffffffu) |
                       ((u32)hi == 0xffffffffu) | ((u32)(hi >> 32) == 0xffffffffu);
            }
            if (!__any((int)bad)) break;
        }

        // ---- early vmem issue (non-protocol): drains under compute ----
        if (t > 0) {
            // deferred out[t-1] store (hp regs still hold h[t-1])
            *(float2*)(out + ((size_t)(b0 + eb) * TDIM + (t - 1)) * HDIM + gcol) =
                make_float2(hp0, hp1);
        }
        // prefetch xproj[t+1]
        u32 nx0 = 0, nx1 = 0, nx2 = 0, nx3 = 0;
        if (t + 1 < TDIM) {
            const u16* xb = xproj + (size_t)(t + 1) * BDIM * G4 +
                            (size_t)(b0 + eb) * G4 + gcol;
            nx0 = *(const u32*)(xb + 0 * HDIM);
            nx1 = *(const u32*)(xb + 1 * HDIM);
            nx2 = *(const u32*)(xb + 2 * HDIM);
            nx3 = *(const u32*)(xb + 3 * HDIM);
        }

        // ---- stage own fragments to LDS ----
        #pragma unroll
        for (int i = 0; i < 4; ++i) {
            const int ks = 4 * w + i;
            *(short8*)&hfrag[(ks * 64 + lane) * 8] = A4[i].s;
        }
        __syncthreads();
        // Here the WHOLE block has verified slab t complete -> all readers of
        // slab t-1 (step t-1 of every producer) are provably done. Safe to
        // re-poison now; store drains under MFMA/gates/elementwise.
        if (t > 0) {
            __hip_atomic_store(
                (u32*)(hbuf + (size_t)((t - 1) & 7) * SLAB_ELEMS +
                       (size_t)bg * GROUP_ELEMS + eidx), 0xffffffffu,
                __ATOMIC_RELAXED, __HIP_MEMORY_SCOPE_AGENT);
        }

        // ---- gates GEMM tile: A from LDS, B from regs ----
        f32x4 acc0 = {0.f, 0.f, 0.f, 0.f}, acc1 = {0.f, 0.f, 0.f, 0.f};
        #pragma unroll
        for (int ks = 0; ks < 16; ++ks) {
            short8 a = *(const short8*)&hfrag[(ks * 64 + lane) * 8];
            acc0 = __builtin_amdgcn_mfma_f32_16x16x32_bf16(a, Bf0[ks], acc0, 0, 0, 0);
            acc1 = __builtin_amdgcn_mfma_f32_16x16x32_bf16(a, Bf1[ks], acc1, 0, 0, 0);
        }
        #pragma unroll
        for (int r = 0; r < 4; ++r) {
            gates[(4 * lhi + r) * 128 + w * 32 + l16]      = acc0[r];
            gates[(4 * lhi + r) * 128 + w * 32 + 16 + l16] = acc1[r];
        }
        __syncthreads();

        // ---- elementwise LSTM + zeta (h_prev from registers) ----
        const float wt = wt_s[t];
        float x0 = bf2f((u16)(xq0 & 0xffff)), x1 = bf2f((u16)(xq0 >> 16));
        float f0 = bf2f((u16)(xq1 & 0xffff)), f1 = bf2f((u16)(xq1 >> 16));
        float g0 = bf2f((u16)(xq2 & 0xffff)), g1 = bf2f((u16)(xq2 >> 16));
        float o0 = bf2f((u16)(xq3 & 0xffff)), o1 = bf2f((u16)(xq3 >> 16));

        float gi0 = gates[eb * 128 + 0 * 32 + j0]     + x0;
        float gi1 = gates[eb * 128 + 0 * 32 + j0 + 1] + x1;
        float gf0 = gates[eb * 128 + 1 * 32 + j0]     + f0;
        float gf1 = gates[eb * 128 + 1 * 32 + j0 + 1] + f1;
        float gg0 = gates[eb * 128 + 2 * 32 + j0]     + g0;
        float gg1 = gates[eb * 128 + 2 * 32 + j0 + 1] + g1;
        float go0 = gates[eb * 128 + 3 * 32 + j0]     + o0;
        float go1 = gates[eb * 128 + 3 * 32 + j0 + 1] + o1;

        float cn0 = fsig(gf0) * creg0 + fsig(gi0) * ftanh(gg0);
        float cn1 = fsig(gf1) * creg1 + fsig(gi1) * ftanh(gg1);
        float ho0 = fsig(go0) * ftanh(cn0) + wt * hp0;
        float ho1 = fsig(go1) * ftanh(cn1) + wt * hp1;
        creg0 = cn0; creg1 = cn1;
        hp0 = ho0; hp1 = ho1;

        // ---- publish h[t+1]: the ONLY vmem op before the next poll ----
        u32 hw = (u32)f2bf(ho0) | ((u32)f2bf(ho1) << 16);
        __hip_atomic_store(
            (u32*)(hbuf + (size_t)((t + 1) & 7) * SLAB_ELEMS +
                   (size_t)bg * GROUP_ELEMS + eidx), hw,
            __ATOMIC_RELAXED, __HIP_MEMORY_SCOPE_AGENT);

        // rotate xproj prefetch regs
        xq0 = nx0; xq1 = nx1; xq2 = nx2; xq3 = nx3;
    }

    // ---- tail: out[T-1], h_final, c_final ----
    *(float2*)(out + ((size_t)(b0 + eb) * TDIM + (TDIM - 1)) * HDIM + gcol) =
        make_float2(hp0, hp1);
    size_t base = (size_t)BDIM * TDIM * HDIM;
    *(float2*)(out + base + (size_t)(b0 + eb) * HDIM + gcol) =
        make_float2(hp0, hp1);
    *(float2*)(out + base + (size_t)BDIM * HDIM + (size_t)(b0 + eb) * HDIM + gcol) =
        make_float2(creg0, creg1);
}

// ---------------------------------------------------------------------------
extern "C" void kernel_launch(void* const* d_in, const int* in_sizes, int n_in,
                              void* d_out, int out_size, void* d_ws, size_t ws_size,
                              hipStream_t stream) {
    const float* x       = (const float*)d_in[0];
    const float* Wih     = (const float*)d_in[1];
    const float* Whh     = (const float*)d_in[2];
    const float* bih     = (const float*)d_in[3];
    const float* bhh     = (const float*)d_in[4];
    const float* log_phi = (const float*)d_in[5];
    const float* gammas  = (const float*)d_in[6];
    float* out = (float*)d_out;

    char* ws = (char*)d_ws;
    u16*   whh_bf = (u16*)(ws);                               // 2 MB
    float* bias   = (float*)(ws + (2u << 20));                // 8 KB
    float* wfull  = (float*)(ws + (2u << 20) + 8192);         // 4 KB
    u16*   hbuf   = (u16*)(ws + (3u << 20));                  // 512 KB ring
    u16*   xproj  = (u16*)(ws + (4u << 20));                  // 256 MB

    prep_kernel<<<dim3(4096), dim3(256), 0, stream>>>(
        Whh, bih, bhh, log_phi, gammas, whh_bf, bias, wfull, (u32*)hbuf);

    xproj_gemm<<<dim3(512, 16), dim3(256), 0, stream>>>(x, Wih, bias, xproj);

    scan_kernel<<<dim3(64), dim3(256), 0, stream>>>(
        whh_bf, wfull, xproj, hbuf, out);
}

// Round 13
// 2672.643 us; speedup vs baseline: 5.9943x; 1.0183x over previous
//
#include <hip/hip_runtime.h>

#define BDIM 64
#define TDIM 1024
#define IDIM 512
#define HDIM 512
#define G4   2048
#define DSLAB 8
// slab = full h snapshot in MFMA-frag layout: [group(4)][ks(16)][lane(64)][j(8)]
#define SLAB_ELEMS (BDIM * HDIM)          // 32768 u16 = 64 KB
#define GROUP_ELEMS (16 * HDIM)           // 8192 u16 = 16 KB

typedef unsigned short u16;
typedef unsigned int u32;
typedef unsigned long long u64;
typedef __attribute__((ext_vector_type(8))) short short8;
typedef __attribute__((ext_vector_type(4))) float f32x4;

__device__ __forceinline__ u16 f2bf(float f) {
    union { float f; unsigned u; } v; v.f = f;
    unsigned u = v.u;
    return (u16)((u + 0x7fffu + ((u >> 16) & 1u)) >> 16);
}
__device__ __forceinline__ float bf2f(u16 h) {
    union { unsigned u; float f; } v; v.u = ((unsigned)h) << 16;
    return v.f;
}
// fast saturation-safe sigmoid/tanh (v_exp_f32 + v_rcp_f32; bf16 rounding dominates)
__device__ __forceinline__ float fsig(float x) {
    float e = __builtin_amdgcn_exp2f(x * -1.4426950408889634f);
    return __builtin_amdgcn_rcpf(1.0f + e);
}
__device__ __forceinline__ float ftanh(float x) {
    float e = __builtin_amdgcn_exp2f(x * -2.8853900817779268f);
    return 2.0f * __builtin_amdgcn_rcpf(1.0f + e) - 1.0f;
}

// ---------------------------------------------------------------------------
// prep: cast W_hh -> bf16, bias = b_ih + b_hh, w_full[t];
// hbuf ring: slab 0 = zeros (h0), slabs 1..7 = 0xFFFFFFFF poison.
// ---------------------------------------------------------------------------
__global__ void prep_kernel(const float* __restrict__ Whh,
                            const float* __restrict__ bih,
                            const float* __restrict__ bhh,
                            const float* __restrict__ log_phi,
                            const float* __restrict__ gammas,
                            u16* __restrict__ whh_bf,
                            float* __restrict__ bias,
                            float* __restrict__ wfull,
                            u32* __restrict__ hbuf32) {
    int idx = blockIdx.x * 256 + threadIdx.x;
    if (idx < G4 * HDIM) whh_bf[idx] = f2bf(Whh[idx]);
    if (idx < G4) bias[idx] = bih[idx] + bhh[idx];
    if (idx < DSLAB * (SLAB_ELEMS / 2))
        hbuf32[idx] = (idx < (SLAB_ELEMS / 2)) ? 0u : 0xffffffffu;
    if (idx < TDIM) {
        float acc = 0.0f;
        #pragma unroll
        for (int m = 0; m < 15; ++m) {
            float lp = log_phi[m];
            float sp = (lp > 15.0f) ? lp : log1pf(expf(lp));
            acc += sp * cosf((float)idx * gammas[m]);
        }
        wfull[idx] = 0.4f * acc / 15.0f;
    }
}

// ---------------------------------------------------------------------------
// xproj GEMM: [65536 x 2048] = x[65536 x 512] * W_ih[2048 x 512]^T + bias
// Output layout: xproj[t][b][n] bf16.
// ---------------------------------------------------------------------------
__global__ __launch_bounds__(256) void xproj_gemm(
        const float* __restrict__ X, const float* __restrict__ Wih,
        const float* __restrict__ bias, u16* __restrict__ xproj) {
    const int tid  = threadIdx.x;
    const int m0   = blockIdx.x * 128;
    const int n0   = blockIdx.y * 128;
    const int lane = tid & 63, w = tid >> 6;
    const int l16  = lane & 15, lhi = lane >> 4;
    const int wr   = w >> 1, wc = w & 1;

    __shared__ u16 As[128 * 64];
    __shared__ u16 Bs[128 * 64];

    f32x4 acc[4][4];
    #pragma unroll
    for (int i = 0; i < 4; ++i)
        #pragma unroll
        for (int j = 0; j < 4; ++j) acc[i][j] = (f32x4){0.f, 0.f, 0.f, 0.f};

    for (int kt = 0; kt < 8; ++kt) {
        const int k0 = kt * 64;
        __syncthreads();
        #pragma unroll
        for (int p = 0; p < 4; ++p) {
            int g = p * 256 + tid;
            int row = g >> 3, oct = g & 7;
            const float* src = X + (size_t)(m0 + row) * IDIM + k0 + oct * 8;
            float4 v0 = *(const float4*)src;
            float4 v1 = *(const float4*)(src + 4);
            short8 u;
            u[0] = (short)f2bf(v0.x); u[1] = (short)f2bf(v0.y);
            u[2] = (short)f2bf(v0.z); u[3] = (short)f2bf(v0.w);
            u[4] = (short)f2bf(v1.x); u[5] = (short)f2bf(v1.y);
            u[6] = (short)f2bf(v1.z); u[7] = (short)f2bf(v1.w);
            int so = (oct ^ (row & 7)) * 8;
            *(short8*)&As[row * 64 + so] = u;
        }
        #pragma unroll
        for (int p = 0; p < 4; ++p) {
            int g = p * 256 + tid;
            int row = g >> 3, oct = g & 7;
            const float* src = Wih + (size_t)(n0 + row) * IDIM + k0 + oct * 8;
            float4 v0 = *(const float4*)src;
            float4 v1 = *(const float4*)(src + 4);
            short8 u;
            u[0] = (short)f2bf(v0.x); u[1] = (short)f2bf(v0.y);
            u[2] = (short)f2bf(v0.z); u[3] = (short)f2bf(v0.w);
            u[4] = (short)f2bf(v1.x); u[5] = (short)f2bf(v1.y);
            u[6] = (short)f2bf(v1.z); u[7] = (short)f2bf(v1.w);
            int so = (oct ^ (row & 7)) * 8;
            *(short8*)&Bs[row * 64 + so] = u;
        }
        __syncthreads();
        #pragma unroll
        for (int ks = 0; ks < 2; ++ks) {
            short8 a[4], b[4];
            #pragma unroll
            for (int ai = 0; ai < 4; ++ai) {
                int row = 64 * wr + 16 * ai + l16;
                int oct = (4 * ks + lhi) ^ (row & 7);
                a[ai] = *(const short8*)&As[row * 64 + oct * 8];
            }
            #pragma unroll
            for (int bi = 0; bi < 4; ++bi) {
                int row = 64 * wc + 16 * bi + l16;
                int oct = (4 * ks + lhi) ^ (row & 7);
                b[bi] = *(const short8*)&Bs[row * 64 + oct * 8];
            }
            #pragma unroll
            for (int ai = 0; ai < 4; ++ai)
                #pragma unroll
                for (int bi = 0; bi < 4; ++bi)
                    acc[ai][bi] = __builtin_amdgcn_mfma_f32_16x16x32_bf16(
                        a[ai], b[bi], acc[ai][bi], 0, 0, 0);
        }
    }
    float bv[4];
    #pragma unroll
    for (int bi = 0; bi < 4; ++bi) bv[bi] = bias[n0 + 64 * wc + 16 * bi + l16];
    #pragma unroll
    for (int ai = 0; ai < 4; ++ai) {
        int grow_base = m0 + 64 * wr + 16 * ai + 4 * lhi;
        #pragma unroll
        for (int bi = 0; bi < 4; ++bi) {
            int gcol = n0 + 64 * wc + 16 * bi + l16;
            #pragma unroll
            for (int r = 0; r < 4; ++r) {
                int grow = grow_base + r;
                int b = grow >> 10;
                int t = grow & 1023;
                xproj[((size_t)t * BDIM + b) * G4 + gcol] =
                    f2bf(acc[ai][bi][r] + bv[bi]);
            }
        }
    }
}

// ---------------------------------------------------------------------------
// scan v13 = v9 (proven: agent-scope L3 exchange, poison slab ring, wave-
// split polling, early vmem issue, post-barrier re-poison) + split MFMA
// accumulator chains (2x 8-deep independent sub-chains per accumulator) to
// cut the post-detect serial MFMA latency roughly in half.
// ---------------------------------------------------------------------------
__global__ __launch_bounds__(256, 1) void scan_kernel(
        const u16* __restrict__ whh_bf, const float* __restrict__ wfull,
        const u16* __restrict__ xproj, u16* __restrict__ hbuf,
        float* __restrict__ out) {
    const int tid = threadIdx.x;
    const int blk = blockIdx.x;      // 0..63
    const int bg  = blk >> 4;        // 0..3   batch group (16 batches)
    const int cgp = blk & 15;        // 0..15  col group (32 h-cols)
    const int b0  = bg * 16;
    const int c0  = cgp * 32;
    const int lane = tid & 63, w = tid >> 6;
    const int l16 = lane & 15, lhi = lane >> 4;

    __shared__ u16  hfrag[16 * 64 * 8];   // 16 KB: staged A fragments
    __shared__ float gates[16 * 128];     //  8 KB
    __shared__ float wt_s[TDIM];          //  4 KB

    for (int i = tid; i < TDIM; i += 256) wt_s[i] = wfull[i];

    // W_hh B-fragments resident in regs: wave w = gate w, cols c0+l16, c0+16+l16
    short8 Bf0[16], Bf1[16];
    #pragma unroll
    for (int ks = 0; ks < 16; ++ks) {
        int row0 = w * HDIM + c0 + l16;
        int row1 = w * HDIM + c0 + 16 + l16;
        Bf0[ks] = *(const short8*)&whh_bf[(size_t)row0 * HDIM + ks * 32 + lhi * 8];
        Bf1[ks] = *(const short8*)&whh_bf[(size_t)row1 * HDIM + ks * 32 + lhi * 8];
    }

    // elementwise ownership: thread -> (b = tid>>4, cols j0 = 2*(tid&15), j0+1)
    const int eb = tid >> 4;
    const int j0 = 2 * (tid & 15);
    const int gcol = c0 + j0;
    const int ln_e = eb + 16 * (j0 >> 3);
    const size_t eidx = ((size_t)cgp * 64 + ln_e) * 8 + (j0 & 7); // u16 idx, even
    float creg0 = 0.f, creg1 = 0.f;      // cell state
    float hp0 = 0.f, hp1 = 0.f;          // previous h (zeta + deferred out store)

    // prologue: xq_cur = xproj[t=0]
    u32 xq0, xq1, xq2, xq3;
    {
        const u16* xb = xproj + (size_t)(b0 + eb) * G4 + gcol;
        xq0 = *(const u32*)(xb + 0 * HDIM);
        xq1 = *(const u32*)(xb + 1 * HDIM);
        xq2 = *(const u32*)(xb + 2 * HDIM);
        xq3 = *(const u32*)(xb + 3 * HDIM);
    }
    __syncthreads();

    for (int t = 0; t < TDIM; ++t) {
        const u16* hsrc = hbuf + (size_t)(t & 7) * SLAB_ELEMS
                               + (size_t)bg * GROUP_ELEMS;

        // ---- wave w polls ONLY its 4 ks fragments until poison-free ----
        union F { u64 q[2]; short8 s; } A4[4];
        for (;;) {
            u32 bad = 0;
            #pragma unroll
            for (int i = 0; i < 4; ++i) {
                const int ks = 4 * w + i;
                const u64* p = (const u64*)(hsrc + ks * 512 + lane * 8);
                u64 lo = __hip_atomic_load(p, __ATOMIC_RELAXED, __HIP_MEMORY_SCOPE_AGENT);
                u64 hi = __hip_atomic_load(p + 1, __ATOMIC_RELAXED, __HIP_MEMORY_SCOPE_AGENT);
                A4[i].q[0] = lo; A4[i].q[1] = hi;
                bad |= ((u32)lo == 0xffffffffu) | ((u32)(lo >> 32) == 0xffffffffu) |
                       ((u32)hi == 0xffffffffu) | ((u32)(hi >> 32) == 0xffffffffu);
            }
            if (!__any((int)bad)) break;
        }

        // ---- early vmem issue (non-protocol): drains under compute ----
        if (t > 0) {
            // deferred out[t-1] store (hp regs still hold h[t-1])
            *(float2*)(out + ((size_t)(b0 + eb) * TDIM + (t - 1)) * HDIM + gcol) =
                make_float2(hp0, hp1);
        }
        // prefetch xproj[t+1]
        u32 nx0 = 0, nx1 = 0, nx2 = 0, nx3 = 0;
        if (t + 1 < TDIM) {
            const u16* xb = xproj + (size_t)(t + 1) * BDIM * G4 +
                            (size_t)(b0 + eb) * G4 + gcol;
            nx0 = *(const u32*)(xb + 0 * HDIM);
            nx1 = *(const u32*)(xb + 1 * HDIM);
            nx2 = *(const u32*)(xb + 2 * HDIM);
            nx3 = *(const u32*)(xb + 3 * HDIM);
        }

        // ---- stage own fragments to LDS ----
        #pragma unroll
        for (int i = 0; i < 4; ++i) {
            const int ks = 4 * w + i;
            *(short8*)&hfrag[(ks * 64 + lane) * 8] = A4[i].s;
        }
        __syncthreads();
        // Whole block has verified slab t complete -> all readers of slab t-1
        // are provably done -> safe to re-poison (drains under compute).
        if (t > 0) {
            __hip_atomic_store(
                (u32*)(hbuf + (size_t)((t - 1) & 7) * SLAB_ELEMS +
                       (size_t)bg * GROUP_ELEMS + eidx), 0xffffffffu,
                __ATOMIC_RELAXED, __HIP_MEMORY_SCOPE_AGENT);
        }

        // ---- gates GEMM tile: A from LDS, B from regs ----
        // Split each accumulator into two independent 8-deep chains to halve
        // the dependent-MFMA latency on the critical path.
        f32x4 acc0a = {0.f, 0.f, 0.f, 0.f}, acc0b = {0.f, 0.f, 0.f, 0.f};
        f32x4 acc1a = {0.f, 0.f, 0.f, 0.f}, acc1b = {0.f, 0.f, 0.f, 0.f};
        #pragma unroll
        for (int ks = 0; ks < 8; ++ks) {
            short8 a  = *(const short8*)&hfrag[(ks * 64 + lane) * 8];
            short8 a2 = *(const short8*)&hfrag[((ks + 8) * 64 + lane) * 8];
            acc0a = __builtin_amdgcn_mfma_f32_16x16x32_bf16(a,  Bf0[ks],     acc0a, 0, 0, 0);
            acc1a = __builtin_amdgcn_mfma_f32_16x16x32_bf16(a,  Bf1[ks],     acc1a, 0, 0, 0);
            acc0b = __builtin_amdgcn_mfma_f32_16x16x32_bf16(a2, Bf0[ks + 8], acc0b, 0, 0, 0);
            acc1b = __builtin_amdgcn_mfma_f32_16x16x32_bf16(a2, Bf1[ks + 8], acc1b, 0, 0, 0);
        }
        f32x4 acc0 = acc0a + acc0b;
        f32x4 acc1 = acc1a + acc1b;
        #pragma unroll
        for (int r = 0; r < 4; ++r) {
            gates[(4 * lhi + r) * 128 + w * 32 + l16]      = acc0[r];
            gates[(4 * lhi + r) * 128 + w * 32 + 16 + l16] = acc1[r];
        }
        __syncthreads();

        // ---- elementwise LSTM + zeta (h_prev from registers) ----
        const float wt = wt_s[t];
        float x0 = bf2f((u16)(xq0 & 0xffff)), x1 = bf2f((u16)(xq0 >> 16));
        float f0 = bf2f((u16)(xq1 & 0xffff)), f1 = bf2f((u16)(xq1 >> 16));
        float g0 = bf2f((u16)(xq2 & 0xffff)), g1 = bf2f((u16)(xq2 >> 16));
        float o0 = bf2f((u16)(xq3 & 0xffff)), o1 = bf2f((u16)(xq3 >> 16));

        float gi0 = gates[eb * 128 + 0 * 32 + j0]     + x0;
        float gi1 = gates[eb * 128 + 0 * 32 + j0 + 1] + x1;
        float gf0 = gates[eb * 128 + 1 * 32 + j0]     + f0;
        float gf1 = gates[eb * 128 + 1 * 32 + j0 + 1] + f1;
        float gg0 = gates[eb * 128 + 2 * 32 + j0]     + g0;
        float gg1 = gates[eb * 128 + 2 * 32 + j0 + 1] + g1;
        float go0 = gates[eb * 128 + 3 * 32 + j0]     + o0;
        float go1 = gates[eb * 128 + 3 * 32 + j0 + 1] + o1;

        float cn0 = fsig(gf0) * creg0 + fsig(gi0) * ftanh(gg0);
        float cn1 = fsig(gf1) * creg1 + fsig(gi1) * ftanh(gg1);
        float ho0 = fsig(go0) * ftanh(cn0) + wt * hp0;
        float ho1 = fsig(go1) * ftanh(cn1) + wt * hp1;
        creg0 = cn0; creg1 = cn1;
        hp0 = ho0; hp1 = ho1;

        // ---- publish h[t+1]: the ONLY vmem op before the next poll ----
        u32 hw = (u32)f2bf(ho0) | ((u32)f2bf(ho1) << 16);
        __hip_atomic_store(
            (u32*)(hbuf + (size_t)((t + 1) & 7) * SLAB_ELEMS +
                   (size_t)bg * GROUP_ELEMS + eidx), hw,
            __ATOMIC_RELAXED, __HIP_MEMORY_SCOPE_AGENT);

        // rotate xproj prefetch regs
        xq0 = nx0; xq1 = nx1; xq2 = nx2; xq3 = nx3;
    }

    // ---- tail: out[T-1], h_final, c_final ----
    *(float2*)(out + ((size_t)(b0 + eb) * TDIM + (TDIM - 1)) * HDIM + gcol) =
        make_float2(hp0, hp1);
    size_t base = (size_t)BDIM * TDIM * HDIM;
    *(float2*)(out + base + (size_t)(b0 + eb) * HDIM + gcol) =
        make_float2(hp0, hp1);
    *(float2*)(out + base + (size_t)BDIM * HDIM + (size_t)(b0 + eb) * HDIM + gcol) =
        make_float2(creg0, creg1);
}

// ---------------------------------------------------------------------------
extern "C" void kernel_launch(void* const* d_in, const int* in_sizes, int n_in,
                              void* d_out, int out_size, void* d_ws, size_t ws_size,
                              hipStream_t stream) {
    const float* x       = (const float*)d_in[0];
    const float* Wih     = (const float*)d_in[1];
    const float* Whh     = (const float*)d_in[2];
    const float* bih     = (const float*)d_in[3];
    const float* bhh     = (const float*)d_in[4];
    const float* log_phi = (const float*)d_in[5];
    const float* gammas  = (const float*)d_in[6];
    float* out = (float*)d_out;

    char* ws = (char*)d_ws;
    u16*   whh_bf = (u16*)(ws);                               // 2 MB
    float* bias   = (float*)(ws + (2u << 20));                // 8 KB
    float* wfull  = (float*)(ws + (2u << 20) + 8192);         // 4 KB
    u16*   hbuf   = (u16*)(ws + (3u << 20));                  // 512 KB ring
    u16*   xproj  = (u16*)(ws + (4u << 20));                  // 256 MB

    prep_kernel<<<dim3(4096), dim3(256), 0, stream>>>(
        Whh, bih, bhh, log_phi, gammas, whh_bf, bias, wfull, (u32*)hbuf);

    xproj_gemm<<<dim3(512, 16), dim3(256), 0, stream>>>(x, Wih, bias, xproj);

    scan_kernel<<<dim3(64), dim3(256), 0, stream>>>(
        whh_bf, wfull, xproj, hbuf, out);
}